// Round 3
// baseline (478.671 us; speedup 1.0000x reference)
//
#include <hip/hip_runtime.h>

// Circular-pad 3x3 conv, 1 -> 64 channels, fp32.
//   out[b,c,y,x] = bias[c] + sum_{r,s} w[c,0,r,s] * in[b,0,(y-1+r)%600,(x-1+s)%600]
//
// v4: DRAM-page-locality structure. v1/v3 (137 us conv, 2.7 TB/s effective)
// had each wave store 1 KB then jump 1.44 MB (next channel plane) -> ~5600
// concurrent {1KB burst, 1.44MB stride} streams -> every HBM channel visit is
// a page miss (~45% write efficiency, matches 2.7/6.3). The 6.3 TB/s fill's
// streams are sequential. So: one long-lived block per (plane, row-band);
// each block sweeps its 180 KB band of ONE output plane sequentially.
//  - 2048 blocks = 256 planes x 8 bands = 8 blocks/CU, all co-resident, no tail.
//  - per channel: ~16 concurrent sequential write streams -> page hits.
//  - input re-read once per channel (378 MB) but XCD-swizzled so each XCD
//    reads exactly one 1.44 MB input image -> L2-resident, HBM fetch ~6 MB.
//  - weights are block-uniform -> plain registers, no LDS, no barrier.

typedef float v4f __attribute__((ext_vector_type(4)));

#define Bn 4
#define Cn 64
#define Hn 600
#define Wn 600
#define Pn (Bn * Cn)                 // 256 output planes
#define BANDS 8
#define BH (Hn / BANDS)              // 75 rows per band
#define QROW (Wn / 4)                // 150 float4 quads per row
#define QBAND (BH * QROW)            // 11250 quads per band
#define NBLK (Pn * BANDS)            // 2048 blocks (NBLK % 8 == 0 -> bijective swizzle)
#define ITERS ((QBAND + 255) / 256)  // 44 grid-stride steps (last partial: 242)

__global__ __launch_bounds__(256) void conv3x3_circ_kernel(
    const float* __restrict__ x,
    const float* __restrict__ w,
    const float* __restrict__ bias,
    float* __restrict__ out)
{
    // Bijective XCD-chunked swizzle: XCD k owns n in [k*256, (k+1)*256)
    // -> 32 consecutive planes -> exactly one input batch image (1.44 MB)
    // resident in that XCD's 4 MB L2.
    const int bid  = blockIdx.x;
    const int n    = (bid & 7) * (NBLK / 8) + (bid >> 3);
    const int p    = n >> 3;          // plane = b*64 + c   (0..255)
    const int band = n & 7;
    const int c    = p & (Cn - 1);
    const int b    = p >> 6;

    // Block-uniform weights + bias -> registers (loads have provably uniform
    // addresses; L2-hot after the first block touches them).
    const float* wc = w + c * 9;
    const float w00 = wc[0], w01 = wc[1], w02 = wc[2];
    const float w10 = wc[3], w11 = wc[4], w12 = wc[5];
    const float w20 = wc[6], w21 = wc[7], w22 = wc[8];
    const float bi  = bias[c];

    const float* xb = x + (size_t)b * (Hn * Wn);
    float*       ob = out + (size_t)p * (Hn * Wn);

    const int y0 = band * BH;

    for (int it = 0; it < ITERS; ++it) {
        const int qb = it * 256 + (int)threadIdx.x;   // quad index within band
        if (qb >= QBAND) break;                       // only last iteration
        const int yl = qb / QROW;                     // const-div -> magic mul
        const int g  = qb - yl * QROW;
        const int y  = y0 + yl;
        const int x0 = g * 4;

        // Circular neighbor indices (global edges only).
        const int ym = (y == 0)       ? (Hn - 1) : (y - 1);
        const int yp = (y == Hn - 1)  ? 0        : (y + 1);
        const int xm = (x0 == 0)      ? (Wn - 1) : (x0 - 1);
        const int xp = (x0 + 4 == Wn) ? 0        : (x0 + 4);

        const float* rm = xb + ym * Wn;
        const float* rc = xb + y  * Wn;
        const float* rp = xb + yp * Wn;

        // 3x6 neighborhood (cols x0-1 .. x0+4); all L1/L2-hot.
        float r0[6], r1[6], r2[6];
        v4f m;
        r0[0] = rm[xm]; m = *(const v4f*)(rm + x0);
        r0[1] = m.x; r0[2] = m.y; r0[3] = m.z; r0[4] = m.w; r0[5] = rm[xp];
        r1[0] = rc[xm]; m = *(const v4f*)(rc + x0);
        r1[1] = m.x; r1[2] = m.y; r1[3] = m.z; r1[4] = m.w; r1[5] = rc[xp];
        r2[0] = rp[xm]; m = *(const v4f*)(rp + x0);
        r2[1] = m.x; r2[2] = m.y; r2[3] = m.z; r2[4] = m.w; r2[5] = rp[xp];

        v4f o;
        #pragma unroll
        for (int j = 0; j < 4; ++j) {
            float a = bi;
            a += w00 * r0[j] + w01 * r0[j + 1] + w02 * r0[j + 2];
            a += w10 * r1[j] + w11 * r1[j + 1] + w12 * r1[j + 2];
            a += w20 * r2[j] + w21 * r2[j + 1] + w22 * r2[j + 2];
            o[j] = a;
        }

        // Sequential within the band across iterations: each wave's store
        // stream is contiguous -> DRAM page hits. (NT vs plain proven
        // neutral in v1/v3; keep plain so L2 can batch writebacks.)
        *(v4f*)(ob + (size_t)y * Wn + x0) = o;
    }
}

extern "C" void kernel_launch(void* const* d_in, const int* in_sizes, int n_in,
                              void* d_out, int out_size, void* d_ws, size_t ws_size,
                              hipStream_t stream) {
    const float* x    = (const float*)d_in[0];   // (4,1,600,600)
    const float* w    = (const float*)d_in[1];   // (64,1,3,3)
    const float* bias = (const float*)d_in[2];   // (64,)
    float* out        = (float*)d_out;           // (4,64,600,600)

    conv3x3_circ_kernel<<<NBLK, 256, 0, stream>>>(x, w, bias, out);
}

// Round 4
// 374.589 us; speedup vs baseline: 1.2779x; 1.2779x over previous
//
#include <hip/hip_runtime.h>

// Circular-pad 3x3 conv, 1 -> 64 channels, fp32.
//   out[b,c,y,x] = bias[c] + sum_{r,s} w[c,0,r,s] * in[b,0,(y-1+r)%600,(x-1+s)%600]
//
// Ledger: writes pinned at ~140us (2.6 TB/s) across v1 (strided bursts),
// v2 (flat dense), v4 (per-block sequential); NT vs plain neutral. The
// 6.25 TB/s fill differs in store ISSUE DEPTH, not address pattern: it
// streams stores back-to-back (~16KB outstanding/wave) while our c-loop
// interleaves ~120 cycles of FMA per 1KB store and reuses the same output
// VGPRs (store-data registers can't be overwritten until the store drains
// -> implicit vmcnt throttle at unroll depth ~4).
//
// v5: store-concurrency fix. Keep v1's thread mapping (one thread per
// (b,y,quad), 3x6 neighborhood in registers, weights in LDS), but compute
// CHANNELS IN BATCHES OF 16 into o[16] (64 VGPRs), then issue 16
// back-to-back 1KB-per-wave stores. 4x deeper write pipeline per wave.

typedef float v4f __attribute__((ext_vector_type(4)));

#define Bn 4
#define Cn 64
#define Hn 600
#define Wn 600
#define Gn (Wn / 4)              // 150 float4 groups per row
#define TOTAL (Bn * Hn * Gn)     // 360000 threads

__global__ __launch_bounds__(256) void conv3x3_circ_kernel(
    const float* __restrict__ x,
    const float* __restrict__ w,
    const float* __restrict__ bias,
    float* __restrict__ out)
{
    // Weights+bias in LDS, 12 floats/channel -> 3 aligned float4 reads,
    // wave-uniform address -> broadcast.
    __shared__ float lw[Cn * 12];
    const int tid = threadIdx.x;
    for (int idx = tid; idx < Cn * 12; idx += 256) {
        const int c = idx / 12;
        const int k = idx - c * 12;
        float v = 0.0f;
        if (k < 9)       v = w[c * 9 + k];
        else if (k == 9) v = bias[c];
        lw[idx] = v;
    }
    __syncthreads();

    const int i = blockIdx.x * 256 + tid;
    if (i >= TOTAL) return;

    const int g  = i % Gn;
    const int t  = i / Gn;
    const int y  = t % Hn;
    const int b  = t / Hn;
    const int x0 = g * 4;

    // Circular neighbor indices (branch-free selects; only edges differ).
    const int ym = (y == 0)        ? (Hn - 1) : (y - 1);
    const int yp = (y == Hn - 1)   ? 0        : (y + 1);
    const int xm = (x0 == 0)       ? (Wn - 1) : (x0 - 1);
    const int xp = (x0 + 4 == Wn)  ? 0        : (x0 + 4);

    const float* xb = x + (size_t)b * (Hn * Wn);
    const float* rm = xb + ym * Wn;
    const float* rc = xb + y  * Wn;
    const float* rp = xb + yp * Wn;

    // 3 rows x 6 columns of input, loaded once, reused for all 64 channels.
    float r0[6], r1[6], r2[6];
    v4f m;
    r0[0] = rm[xm]; m = *(const v4f*)(rm + x0);
    r0[1] = m.x; r0[2] = m.y; r0[3] = m.z; r0[4] = m.w; r0[5] = rm[xp];
    r1[0] = rc[xm]; m = *(const v4f*)(rc + x0);
    r1[1] = m.x; r1[2] = m.y; r1[3] = m.z; r1[4] = m.w; r1[5] = rc[xp];
    r2[0] = rp[xm]; m = *(const v4f*)(rp + x0);
    r2[1] = m.x; r2[2] = m.y; r2[3] = m.z; r2[4] = m.w; r2[5] = rp[xp];

    float* op = out + (size_t)b * (Cn * Hn * Wn) + (size_t)y * Wn + x0;
    const v4f* lw4 = (const v4f*)lw;

    // 4 batches of 16 channels: compute 16 outputs into registers, then
    // issue 16 back-to-back stores (deep write pipeline per wave).
    for (int cc = 0; cc < Cn; cc += 16) {
        v4f o[16];
        #pragma unroll
        for (int u = 0; u < 16; ++u) {
            const int c = cc + u;
            const v4f wA = lw4[c * 3 + 0];  // w00 w01 w02 w10
            const v4f wB = lw4[c * 3 + 1];  // w11 w12 w20 w21
            const v4f wC = lw4[c * 3 + 2];  // w22 bias pad pad
            #pragma unroll
            for (int j = 0; j < 4; ++j) {
                float a = wC.y;  // bias
                a += wA.x * r0[j] + wA.y * r0[j + 1] + wA.z * r0[j + 2];
                a += wA.w * r1[j] + wB.x * r1[j + 1] + wB.y * r1[j + 2];
                a += wB.z * r2[j] + wB.w * r2[j + 1] + wC.x * r2[j + 2];
                o[u][j] = a;
            }
        }
        #pragma unroll
        for (int u = 0; u < 16; ++u) {
            *(v4f*)(op + (size_t)(cc + u) * (Hn * Wn)) = o[u];
        }
    }
}

extern "C" void kernel_launch(void* const* d_in, const int* in_sizes, int n_in,
                              void* d_out, int out_size, void* d_ws, size_t ws_size,
                              hipStream_t stream) {
    const float* x    = (const float*)d_in[0];   // (4,1,600,600)
    const float* w    = (const float*)d_in[1];   // (64,1,3,3)
    const float* bias = (const float*)d_in[2];   // (64,)
    float* out        = (float*)d_out;           // (4,64,600,600)

    const int blocks = (TOTAL + 255) / 256;      // 1407
    conv3x3_circ_kernel<<<blocks, 256, 0, stream>>>(x, w, bias, out);
}